// Round 9
// baseline (220.971 us; speedup 1.0000x reference)
//
#include <hip/hip_runtime.h>
#include <math.h>

#define NPOS 4096
#define DCH  512
#define HD   32
#define NH   16
#define KW   9
#define DIL  3
#define PAD  12
#define TILE   32                  // tokens per block == per wave
#define NTILES (NPOS / TILE)       // 128
#define SPANT  (TILE + 2*PAD)      // 56 tokens staged per wave
#define RS     60                  // LDS row stride floats (56 + 4 pad).
                                   // 60%32=28 -> row bank rotation (no same-bank rows);
                                   // 15 chunks/row -> chunk c at float 4c EXACTLY LINEAR
                                   // (row*60 + c4*4 = 4*(15*row + c4)) as gload16 requires.
#define ROWC   (RS / 4)            // 15 16B chunks per row
#define KCHK   (HD * ROWC)         // 480 chunks: K rows only
#define KINST  8                   // ceil(480/64) staging insts (inst 7 half-active)
#define CSPL   8                   // channel-split lanes per token-group
#define CPT    (HD / CSPL)         // 4 channels per thread
#define TPT    4                   // tokens per thread (8 groups x 4)
#define WSPAN  28                  // 4 tokens x 9 taps span 28 tokens
#define WCHK   (WSPAN / 4)         // 7 float4 chunks per window
#define NXCD   8

// Native clang vector for nontemporal builtin (HIP float4 is a class type).
typedef float floatx4 __attribute__((ext_vector_type(4)));

// Direct global->LDS (16B). LDS dest linear in lane (c = it*64 + lane).
__device__ __forceinline__ void gload16(const float* g, float* l) {
    __builtin_amdgcn_global_load_lds(
        (const __attribute__((address_space(1))) void*)g,
        (__attribute__((address_space(3))) void*)l,
        16, 0, 0);
}

// Butterfly sum over 8 consecutive lanes — pure VALU via DPP.
__device__ __forceinline__ float dpp_sum8(float x) {
    int t;
    t = __builtin_amdgcn_update_dpp(0, __float_as_int(x), 0xB1, 0xF, 0xF, true);
    x += __int_as_float(t);
    t = __builtin_amdgcn_update_dpp(0, __float_as_int(x), 0x4E, 0xF, 0xF, true);
    x += __int_as_float(t);
    t = __builtin_amdgcn_update_dpp(0, __float_as_int(x), 0x141, 0xF, 0xF, true);
    x += __int_as_float(t);
    return x;
}

// Direct-global V window row: 7 x global_load_dwordx4 into registers.
// Per-chunk clamp to [0, NPOS-4]; clamp only fires on chunks whose taps are
// ALL invalid (w0 % 4 == 0 aligns the boundary), masked to zero in softmax.
__device__ __forceinline__ void vload_row(const float* row, int w0, float* w) {
#pragma unroll
    for (int u = 0; u < WCHK; ++u) {
        int g0 = min(max(w0 + 4 * u, 0), NPOS - 4);
        float4 x = *(const float4*)(row + g0);
        w[4*u] = x.x; w[4*u+1] = x.y; w[4*u+2] = x.z; w[4*u+3] = x.w;
    }
}

__global__ __launch_bounds__(64, 4) void dilate_attn_kernel(
    const float* __restrict__ q,
    const float* __restrict__ k,
    const float* __restrict__ v,
    float* __restrict__ out)
{
    // Per-wave private K staging only: 7680 B -> 4 waves/SIMD residency.
    __shared__ float ks[HD * RS];

    // ---- XCD-aware remap: all 128 tiles of a bh land on ONE XCD, ----------
    // consecutive tiles consecutive in dispatch (halo lines L2-hot).
    const int id   = blockIdx.x;
    const int xcd  = id & (NXCD - 1);
    const int seq  = id >> 3;                    // 0..1023
    const int tile = seq & (NTILES - 1);         // 0..127
    const int bh   = ((seq >> 7) << 3) | xcd;    // 0..63

    const int n0t  = tile * TILE;
    const int ws   = n0t - PAD;                  // staged span start (may be <0)

    const size_t cb = (size_t)bh * HD * NPOS;
    const float* qg = q + cb;
    const float* kg = k + cb;
    const float* vg = v + cb;

    const int tid = threadIdx.x;                 // 0..63 (one wave)
    const int cs  = tid & (CSPL - 1);            // channel octet slot
    const int lg  = tid >> 3;                    // 0..7: token group
    const int n0  = n0t + lg * TPT;              // first token this thread owns
    const int w0  = n0 - PAD;                    // per-thread window start

    const float scale = 0.17677669529663687f;    // 32^-0.5

    // ---- issue q first (4 insts, oldest in vmcnt order) --------------------
    float4 qv[CPT];
#pragma unroll
    for (int i = 0; i < CPT; ++i)
        qv[i] = *(const float4*)(qg + (size_t)(cs * CPT + i) * NPOS + n0);
    asm volatile("" ::: "memory");               // pin q before K

    // ---- stage K span: 8 x global_load_lds_dwordx4, no barrier ever --------
    // Per-lane global src clamped; clamped chunks are all-invalid-tap only.
#pragma unroll
    for (int it = 0; it < KINST; ++it) {
        int c = it * 64 + tid;                   // 0..511
        if (c < KCHK) {                          // prefix-active tail guard
            int row = c / ROWC;                  // 0..31
            int c4  = c - row * ROWC;            // 0..14
            int g0  = min(max(ws + c4 * 4, 0), NPOS - 4);
            gload16(kg + (size_t)row * NPOS + g0, &ks[c * 4]);
        }
    }
    asm volatile("" ::: "memory");               // pin K before V row0

    // ---- issue V row0 into registers (latency hides under pass1) ----------
    float vA[WSPAN], vB[WSPAN];
    vload_row(vg + (size_t)(cs * CPT + 0) * NPOS, w0, vA);
    asm volatile("" ::: "memory");               // pin V0 after K

    // ---- wait own q(4)+K(8); V0's 7 loads stay outstanding -----------------
    asm volatile("s_waitcnt vmcnt(7)" ::: "memory");

    // ---- Pass 1: scores from own LDS K -------------------------------------
    float s[TPT][KW];
#pragma unroll
    for (int t = 0; t < TPT; ++t)
#pragma unroll
        for (int j = 0; j < KW; ++j) s[t][j] = 0.0f;

#pragma unroll
    for (int i = 0; i < CPT; ++i) {
        int row = cs * CPT + i;
        float w[WSPAN];
        const float4* wp = (const float4*)&ks[row * RS + lg * TPT];
#pragma unroll
        for (int u = 0; u < WCHK; ++u) {
            float4 x = wp[u];
            w[4*u] = x.x; w[4*u+1] = x.y; w[4*u+2] = x.z; w[4*u+3] = x.w;
        }
        float qt[TPT] = {qv[i].x, qv[i].y, qv[i].z, qv[i].w};
#pragma unroll
        for (int t = 0; t < TPT; ++t)
#pragma unroll
            for (int j = 0; j < KW; ++j)
                s[t][j] = fmaf(qt[t], w[t + 3*j], s[t][j]);
    }

    // ---- issue V row1 (hides under reduce+softmax) -------------------------
    vload_row(vg + (size_t)(cs * CPT + 1) * NPOS, w0, vB);

    // Reduce partials across the 8 channel-split lanes (DPP, no DS ops)
#pragma unroll
    for (int t = 0; t < TPT; ++t)
#pragma unroll
        for (int j = 0; j < KW; ++j)
            s[t][j] = dpp_sum8(s[t][j]);

    // ---- Softmax (tap-mask only for the two edge tiles; wave-uniform) -----
    const bool masked = (tile == 0) || (tile == NTILES - 1);
    if (!masked) {
#pragma unroll
        for (int t = 0; t < TPT; ++t) {
            float m = -INFINITY;
#pragma unroll
            for (int j = 0; j < KW; ++j) {
                float x = s[t][j] * scale;
                s[t][j] = x;
                m = fmaxf(m, x);
            }
            float sum = 0.0f;
#pragma unroll
            for (int j = 0; j < KW; ++j) {
                float e = __expf(s[t][j] - m);
                s[t][j] = e;
                sum += e;
            }
            float inv = 1.0f / sum;
#pragma unroll
            for (int j = 0; j < KW; ++j) s[t][j] *= inv;
        }
    } else {
        // invalid taps: logit exactly 0 (Unfold zero-padding), prob zeroed
#pragma unroll
        for (int t = 0; t < TPT; ++t) {
            float vm[KW];
            float m = -INFINITY;
#pragma unroll
            for (int j = 0; j < KW; ++j) {
                vm[j] = ((unsigned)(n0 + t + 3*j - PAD) < NPOS) ? 1.0f : 0.0f;
                float x = s[t][j] * scale * vm[j];
                s[t][j] = x;
                m = fmaxf(m, x);
            }
            float sum = 0.0f;
#pragma unroll
            for (int j = 0; j < KW; ++j) {
                float e = __expf(s[t][j] - m);
                s[t][j] = e;
                sum += e;
            }
            float inv = 1.0f / sum;
#pragma unroll
            for (int j = 0; j < KW; ++j)
                s[t][j] *= inv * vm[j];
        }
    }

    // ---- Pass 2: rolling vA/vB register pipeline (compiler-managed waits) --
    float o[TPT][CPT];
#pragma unroll
    for (int t = 0; t < TPT; ++t)
#pragma unroll
        for (int i = 0; i < CPT; ++i) o[t][i] = 0.0f;

    // i=0 from vA, then refill vA with row2 (WAR: issue after consumption)
#pragma unroll
    for (int t = 0; t < TPT; ++t)
#pragma unroll
        for (int j = 0; j < KW; ++j)
            o[t][0] = fmaf(s[t][j], vA[t + 3*j], o[t][0]);
    vload_row(vg + (size_t)(cs * CPT + 2) * NPOS, w0, vA);

    // i=1 from vB, then refill vB with row3
#pragma unroll
    for (int t = 0; t < TPT; ++t)
#pragma unroll
        for (int j = 0; j < KW; ++j)
            o[t][1] = fmaf(s[t][j], vB[t + 3*j], o[t][1]);
    vload_row(vg + (size_t)(cs * CPT + 3) * NPOS, w0, vB);

    // i=2 from vA
#pragma unroll
    for (int t = 0; t < TPT; ++t)
#pragma unroll
        for (int j = 0; j < KW; ++j)
            o[t][2] = fmaf(s[t][j], vA[t + 3*j], o[t][2]);

    // i=3 from vB
#pragma unroll
    for (int t = 0; t < TPT; ++t)
#pragma unroll
        for (int j = 0; j < KW; ++j)
            o[t][3] = fmaf(s[t][j], vB[t + 3*j], o[t][3]);

    // ---- Store: one NT float4 per token (128B/token across 8 cs lanes) ----
    const int b  = bh >> 4;
    const int hh = bh & (NH - 1);
#pragma unroll
    for (int t = 0; t < TPT; ++t) {
        float* op = out + ((size_t)(b * NPOS + n0 + t)) * DCH + hh * HD + cs * CPT;
        floatx4 val = {o[t][0], o[t][1], o[t][2], o[t][3]};
        __builtin_nontemporal_store(val, (floatx4*)op);
    }
}

extern "C" void kernel_launch(void* const* d_in, const int* in_sizes, int n_in,
                              void* d_out, int out_size, void* d_ws, size_t ws_size,
                              hipStream_t stream) {
    const float* q = (const float*)d_in[0];
    const float* k = (const float*)d_in[1];
    const float* v = (const float*)d_in[2];
    float* out = (float*)d_out;

    const int grid = 4 * NH * NTILES;   // 64 bh * 128 tiles = 8192 one-wave blocks
    hipLaunchKernelGGL(dilate_attn_kernel, dim3(grid), dim3(64), 0, stream,
                       q, k, v, out);
}

// Round 10
// 146.601 us; speedup vs baseline: 1.5073x; 1.5073x over previous
//
#include <hip/hip_runtime.h>
#include <math.h>

#define NPOS 4096
#define DCH  512
#define HD   32
#define NH   16
#define KW   9
#define DIL  3
#define PAD  12
#define TILE   64                  // tokens per block (2 waves)
#define NTILES (NPOS / TILE)       // 64
#define SPANT  (TILE + 2*PAD)      // 88 tokens staged per block
#define RS     SPANT               // 88: 88%32=24 -> bank rotation across rows;
                                   // 22 chunks/row -> chunk c at float 4c EXACTLY
                                   // LINEAR (row*88 + c4*4 = 4*(22*row + c4)).
#define ROWC   (RS / 4)            // 22 16B chunks per row
#define NCHK   (2 * HD * ROWC)     // 1408 chunks: K rows 0..31 then V rows 32..63
#define NTHR   128
#define NINST  (NCHK / NTHR)       // 11 staging insts per thread (exact)
#define CSPL   8                   // channel-split lanes per token-group
#define CPT    (HD / CSPL)         // 4 channels per thread
#define TPT    4                   // tokens per thread (16 groups x 4 = 64)
#define WSPAN  28                  // 4 tokens x 9 taps span 28 tokens
#define WCHK   (WSPAN / 4)         // 7 float4 chunks per window
#define NXCD   8

// Native clang vector for nontemporal builtin (HIP float4 is a class type).
typedef float floatx4 __attribute__((ext_vector_type(4)));

// Direct global->LDS (16B). LDS dest linear in lane within each wave:
// addr_bytes = 16*(it*128 + tid) = waveconst + 16*lane.
__device__ __forceinline__ void gload16(const float* g, float* l) {
    __builtin_amdgcn_global_load_lds(
        (const __attribute__((address_space(1))) void*)g,
        (__attribute__((address_space(3))) void*)l,
        16, 0, 0);
}

// Butterfly sum over 8 consecutive lanes — pure VALU via DPP.
__device__ __forceinline__ float dpp_sum8(float x) {
    int t;
    t = __builtin_amdgcn_update_dpp(0, __float_as_int(x), 0xB1, 0xF, 0xF, true);
    x += __int_as_float(t);
    t = __builtin_amdgcn_update_dpp(0, __float_as_int(x), 0x4E, 0xF, 0xF, true);
    x += __int_as_float(t);
    t = __builtin_amdgcn_update_dpp(0, __float_as_int(x), 0x141, 0xF, 0xF, true);
    x += __int_as_float(t);
    return x;
}

__global__ __launch_bounds__(NTHR, 3) void dilate_attn_kernel(
    const float* __restrict__ q,
    const float* __restrict__ k,
    const float* __restrict__ v,
    float* __restrict__ out)
{
    // Shared staging for the 2-wave block: K rows then V rows. 22528 B.
    __shared__ float kv[2 * HD * RS];
    float* const ks = kv;
    float* const vs = kv + HD * RS;

    // ---- XCD-aware remap: all 64 tiles of a bh land on ONE XCD, -----------
    // consecutive tiles consecutive in dispatch (halo lines L2-hot).
    const int id   = blockIdx.x;
    const int xcd  = id & (NXCD - 1);
    const int seq  = id >> 3;                    // 0..511
    const int tile = seq & (NTILES - 1);         // 0..63
    const int bh   = ((seq >> 6) << 3) | xcd;    // 0..63

    const int n0t  = tile * TILE;
    const int ws   = n0t - PAD;                  // staged span start (may be <0)

    const size_t cb = (size_t)bh * HD * NPOS;
    const float* qg = q + cb;
    const float* kg = k + cb;
    const float* vg = v + cb;

    const int tid = threadIdx.x;                 // 0..127
    const int cs  = tid & (CSPL - 1);            // channel octet slot
    const int lg  = tid >> 3;                    // 0..15: token group
    const int n0  = n0t + lg * TPT;              // first token this thread owns

    const float scale = 0.17677669529663687f;    // 32^-0.5

    // ---- issue q first (4 insts/wave, oldest in vmcnt order) ---------------
    float4 qv[CPT];
#pragma unroll
    for (int i = 0; i < CPT; ++i)
        qv[i] = *(const float4*)(qg + (size_t)(cs * CPT + i) * NPOS + n0);
    asm volatile("" ::: "memory");               // pin q before KV

    // ---- stage K+V span: 11 x global_load_lds_dwordx4 per thread -----------
    // Per-lane global src CLAMPED to [0, NPOS-4]: ws % 4 == 0 aligns the
    // boundary, so a clamped chunk's taps are ALL invalid (masked to exact
    // zero in softmax); valid taps always come from unclamped chunks.
#pragma unroll
    for (int it = 0; it < NINST; ++it) {
        int c   = it * NTHR + tid;               // 0..1407
        int row = c / ROWC;                      // 0..63 (K: 0..31, V: 32..63)
        int c4  = c - row * ROWC;                // 0..21
        int g0  = min(max(ws + c4 * 4, 0), NPOS - 4);
        const float* src = (row < HD)
            ? kg + (size_t)row * NPOS + g0
            : vg + (size_t)(row - HD) * NPOS + g0;
        gload16(src, &kv[c * 4]);                // LDS dest linear in lane
    }

    // ---- wait own q + all own K-insts retired; V stays in flight -----------
    // In-order per wave: q(4) + staging(11). vmcnt(5) => >=10 retired =
    // q(4) + staging insts 0..5. Wave0's K insts are 0..5 (chunks<704),
    // wave1's are 0..4 — both covered. Barrier makes ALL K LDS-visible.
    asm volatile("s_waitcnt vmcnt(5)" ::: "memory");
    __builtin_amdgcn_s_barrier();
    asm volatile("" ::: "memory");

    // ---- Pass 1: scores from shared LDS K (V staging overlapped) -----------
    float s[TPT][KW];
#pragma unroll
    for (int t = 0; t < TPT; ++t)
#pragma unroll
        for (int j = 0; j < KW; ++j) s[t][j] = 0.0f;

#pragma unroll
    for (int i = 0; i < CPT; ++i) {
        int row = cs * CPT + i;
        float w[WSPAN];
        const float4* wp = (const float4*)&ks[row * RS + lg * TPT];
#pragma unroll
        for (int u = 0; u < WCHK; ++u) {
            float4 x = wp[u];
            w[4*u] = x.x; w[4*u+1] = x.y; w[4*u+2] = x.z; w[4*u+3] = x.w;
        }
        float qt[TPT] = {qv[i].x, qv[i].y, qv[i].z, qv[i].w};
#pragma unroll
        for (int t = 0; t < TPT; ++t)
#pragma unroll
            for (int j = 0; j < KW; ++j)
                s[t][j] = fmaf(qt[t], w[t + 3*j], s[t][j]);
    }

    // Reduce partials across the 8 channel-split lanes (DPP, no DS ops)
#pragma unroll
    for (int t = 0; t < TPT; ++t)
#pragma unroll
        for (int j = 0; j < KW; ++j)
            s[t][j] = dpp_sum8(s[t][j]);

    // ---- Softmax (tap-mask only for the two edge tiles; block-uniform) ----
    const bool masked = (tile == 0) || (tile == NTILES - 1);
    if (!masked) {
#pragma unroll
        for (int t = 0; t < TPT; ++t) {
            float m = -INFINITY;
#pragma unroll
            for (int j = 0; j < KW; ++j) {
                float x = s[t][j] * scale;
                s[t][j] = x;
                m = fmaxf(m, x);
            }
            float sum = 0.0f;
#pragma unroll
            for (int j = 0; j < KW; ++j) {
                float e = __expf(s[t][j] - m);
                s[t][j] = e;
                sum += e;
            }
            float inv = 1.0f / sum;
#pragma unroll
            for (int j = 0; j < KW; ++j) s[t][j] *= inv;
        }
    } else {
        // invalid taps: logit exactly 0 (Unfold zero-padding), prob zeroed
#pragma unroll
        for (int t = 0; t < TPT; ++t) {
            float vm[KW];
            float m = -INFINITY;
#pragma unroll
            for (int j = 0; j < KW; ++j) {
                vm[j] = ((unsigned)(n0 + t + 3*j - PAD) < NPOS) ? 1.0f : 0.0f;
                float x = s[t][j] * scale * vm[j];
                s[t][j] = x;
                m = fmaxf(m, x);
            }
            float sum = 0.0f;
#pragma unroll
            for (int j = 0; j < KW; ++j) {
                float e = __expf(s[t][j] - m);
                s[t][j] = e;
                sum += e;
            }
            float inv = 1.0f / sum;
#pragma unroll
            for (int j = 0; j < KW; ++j)
                s[t][j] *= inv * vm[j];
        }
    }

    // ---- all V retired + visible to both waves -----------------------------
    asm volatile("s_waitcnt vmcnt(0)" ::: "memory");
    __builtin_amdgcn_s_barrier();
    asm volatile("" ::: "memory");

    // ---- Pass 2: output from shared LDS V ----------------------------------
    float o[TPT][CPT];
#pragma unroll
    for (int t = 0; t < TPT; ++t)
#pragma unroll
        for (int i = 0; i < CPT; ++i) o[t][i] = 0.0f;

#pragma unroll
    for (int i = 0; i < CPT; ++i) {
        int row = cs * CPT + i;
        float w[WSPAN];
        const float4* wp = (const float4*)&vs[row * RS + lg * TPT];
#pragma unroll
        for (int u = 0; u < WCHK; ++u) {
            float4 x = wp[u];
            w[4*u] = x.x; w[4*u+1] = x.y; w[4*u+2] = x.z; w[4*u+3] = x.w;
        }
#pragma unroll
        for (int t = 0; t < TPT; ++t)
#pragma unroll
            for (int j = 0; j < KW; ++j)
                o[t][i] = fmaf(s[t][j], w[t + 3*j], o[t][i]);
    }

    // ---- Store: one NT float4 per token (128B/token across 8 cs lanes) ----
    const int b  = bh >> 4;
    const int hh = bh & (NH - 1);
#pragma unroll
    for (int t = 0; t < TPT; ++t) {
        float* op = out + ((size_t)(b * NPOS + n0 + t)) * DCH + hh * HD + cs * CPT;
        floatx4 val = {o[t][0], o[t][1], o[t][2], o[t][3]};
        __builtin_nontemporal_store(val, (floatx4*)op);
    }
}

extern "C" void kernel_launch(void* const* d_in, const int* in_sizes, int n_in,
                              void* d_out, int out_size, void* d_ws, size_t ws_size,
                              hipStream_t stream) {
    const float* q = (const float*)d_in[0];
    const float* k = (const float*)d_in[1];
    const float* v = (const float*)d_in[2];
    float* out = (float*)d_out;

    const int grid = 4 * NH * NTILES;   // 64 bh * 64 tiles = 4096 two-wave blocks
    hipLaunchKernelGGL(dilate_attn_kernel, dim3(grid), dim3(NTHR), 0, stream,
                       q, k, v, out);
}

// Round 11
// 142.372 us; speedup vs baseline: 1.5521x; 1.0297x over previous
//
#include <hip/hip_runtime.h>
#include <math.h>

#define NPOS 4096
#define DCH  512
#define HD   32
#define NH   16
#define KW   9
#define DIL  3
#define PAD  12
#define TILE   32                  // tokens per block == per wave
#define NTILES (NPOS / TILE)       // 128
#define SPANT  (TILE + 2*PAD)      // 56 tokens staged per wave (K only)
#define RS     60                  // LDS row stride floats (56 + 4 pad).
                                   // cs-step stride = 4*60 = 240 ≡ 16 mod 32 banks ->
                                   // 2-way lane aliasing (free, m136); 15 chunks/row ->
                                   // chunk c at float 4c EXACTLY LINEAR as gload16 needs.
#define ROWC   (RS / 4)            // 15 16B chunks per row
#define KCHK   (HD * ROWC)         // 480 K chunks
#define KINST  8                   // ceil(480/64); inst 7 prefix-active (lanes 0..31)
#define CSPL   8                   // channel-split lanes per token-group
#define CPT    (HD / CSPL)         // 4 channels per thread
#define TPT    4                   // tokens per thread (8 groups x 4)
#define WSPAN  28                  // 4 tokens x 9 taps span 28 tokens
#define WCHK   (WSPAN / 4)         // 7 float4 chunks per window
#define NXCD   8

// Native clang vector for nontemporal builtin (HIP float4 is a class type).
typedef float floatx4 __attribute__((ext_vector_type(4)));

// Direct global->LDS (16B). LDS dest linear in lane (c = it*64 + lane).
__device__ __forceinline__ void gload16(const float* g, float* l) {
    __builtin_amdgcn_global_load_lds(
        (const __attribute__((address_space(1))) void*)g,
        (__attribute__((address_space(3))) void*)l,
        16, 0, 0);
}

// Butterfly sum over 8 consecutive lanes — pure VALU via DPP.
__device__ __forceinline__ float dpp_sum8(float x) {
    int t;
    t = __builtin_amdgcn_update_dpp(0, __float_as_int(x), 0xB1, 0xF, 0xF, true);
    x += __int_as_float(t);
    t = __builtin_amdgcn_update_dpp(0, __float_as_int(x), 0x4E, 0xF, 0xF, true);
    x += __int_as_float(t);
    t = __builtin_amdgcn_update_dpp(0, __float_as_int(x), 0x141, 0xF, 0xF, true);
    x += __int_as_float(t);
    return x;
}

// V window row straight from global: 7 x global_load_dwordx4 into registers.
// Per-chunk clamp to [0, NPOS-4]; w0 % 4 == 0 aligns the boundary, so a
// clamped chunk's taps are ALL invalid -> their probability is exactly 0 and
// 0 * finite-garbage = 0 in the PV accumulate.
__device__ __forceinline__ void vload_row(const float* row, int w0, float* w) {
#pragma unroll
    for (int u = 0; u < WCHK; ++u) {
        int g0 = min(max(w0 + 4 * u, 0), NPOS - 4);
        float4 x = *(const float4*)(row + g0);
        w[4*u] = x.x; w[4*u+1] = x.y; w[4*u+2] = x.z; w[4*u+3] = x.w;
    }
}

__global__ __launch_bounds__(64) void dilate_attn_kernel(
    const float* __restrict__ q,
    const float* __restrict__ k,
    const float* __restrict__ v,
    float* __restrict__ out)
{
    // Per-wave private K staging only: 7680 B.
    __shared__ float ks[HD * RS];

    // ---- XCD-aware remap: all 128 tiles of a bh land on ONE XCD, ----------
    // consecutive tiles consecutive in dispatch (halo lines L2-hot).
    const int id   = blockIdx.x;
    const int xcd  = id & (NXCD - 1);
    const int seq  = id >> 3;                    // 0..1023
    const int tile = seq & (NTILES - 1);         // 0..127
    const int bh   = ((seq >> 7) << 3) | xcd;    // 0..63

    const int n0t  = tile * TILE;
    const int ws   = n0t - PAD;                  // staged span start (may be <0)

    const size_t cb = (size_t)bh * HD * NPOS;
    const float* qg = q + cb;
    const float* kg = k + cb;
    const float* vg = v + cb;

    const int tid = threadIdx.x;                 // 0..63 (one wave)
    const int cs  = tid & (CSPL - 1);            // channel octet slot
    const int lg  = tid >> 3;                    // 0..7: token group
    const int n0  = n0t + lg * TPT;              // first token this thread owns
    const int w0  = n0 - PAD;                    // per-thread window start (%4==0)

    const float scale = 0.17677669529663687f;    // 32^-0.5

    // ---- issue q first (4 insts, oldest in vmcnt order) --------------------
    float4 qv[CPT];
#pragma unroll
    for (int i = 0; i < CPT; ++i)
        qv[i] = *(const float4*)(qg + (size_t)(cs * CPT + i) * NPOS + n0);
    asm volatile("" ::: "memory");               // pin q before K

    // ---- stage K span: 8 x global_load_lds_dwordx4, no barrier ever --------
    // Per-lane global src clamped; clamped chunks are all-invalid-tap only.
#pragma unroll
    for (int it = 0; it < KINST; ++it) {
        int c = it * 64 + tid;                   // 0..511
        if (c < KCHK) {                          // prefix-active tail guard
            int row = c / ROWC;                  // 0..31
            int c4  = c - row * ROWC;            // 0..14
            int g0  = min(max(ws + c4 * 4, 0), NPOS - 4);
            gload16(kg + (size_t)row * NPOS + g0, &ks[c * 4]);
        }
    }
    asm volatile("" ::: "memory");               // pin K before V row0

    // ---- issue V row0 into the single register window (hides under pass1) --
    float w[WSPAN];
    vload_row(vg + (size_t)(cs * CPT + 0) * NPOS, w0, w);

    // ---- wait own q(4)+K(8) retired; V0's 7 loads stay outstanding ---------
    asm volatile("s_waitcnt vmcnt(7)" ::: "memory");

    // ---- Pass 1: scores from own LDS K -------------------------------------
    float s[TPT][KW];
#pragma unroll
    for (int t = 0; t < TPT; ++t)
#pragma unroll
        for (int j = 0; j < KW; ++j) s[t][j] = 0.0f;

#pragma unroll
    for (int i = 0; i < CPT; ++i) {
        int row = cs * CPT + i;
        float kw[WSPAN];
        const float4* wp = (const float4*)&ks[row * RS + lg * TPT];
#pragma unroll
        for (int u = 0; u < WCHK; ++u) {
            float4 x = wp[u];
            kw[4*u] = x.x; kw[4*u+1] = x.y; kw[4*u+2] = x.z; kw[4*u+3] = x.w;
        }
        float qt[TPT] = {qv[i].x, qv[i].y, qv[i].z, qv[i].w};
#pragma unroll
        for (int t = 0; t < TPT; ++t)
#pragma unroll
            for (int j = 0; j < KW; ++j)
                s[t][j] = fmaf(qt[t], kw[t + 3*j], s[t][j]);
    }

    // Reduce partials across the 8 channel-split lanes (DPP, no DS ops)
#pragma unroll
    for (int t = 0; t < TPT; ++t)
#pragma unroll
        for (int j = 0; j < KW; ++j)
            s[t][j] = dpp_sum8(s[t][j]);

    // ---- Softmax (tap-mask only for the two edge tiles; wave-uniform) -----
    const bool masked = (tile == 0) || (tile == NTILES - 1);
    if (!masked) {
#pragma unroll
        for (int t = 0; t < TPT; ++t) {
            float m = -INFINITY;
#pragma unroll
            for (int j = 0; j < KW; ++j) {
                float x = s[t][j] * scale;
                s[t][j] = x;
                m = fmaxf(m, x);
            }
            float sum = 0.0f;
#pragma unroll
            for (int j = 0; j < KW; ++j) {
                float e = __expf(s[t][j] - m);
                s[t][j] = e;
                sum += e;
            }
            float inv = 1.0f / sum;
#pragma unroll
            for (int j = 0; j < KW; ++j) s[t][j] *= inv;
        }
    } else {
        // invalid taps: logit exactly 0 (Unfold zero-padding), prob zeroed
#pragma unroll
        for (int t = 0; t < TPT; ++t) {
            float vm[KW];
            float m = -INFINITY;
#pragma unroll
            for (int j = 0; j < KW; ++j) {
                vm[j] = ((unsigned)(n0 + t + 3*j - PAD) < NPOS) ? 1.0f : 0.0f;
                float x = s[t][j] * scale * vm[j];
                s[t][j] = x;
                m = fmaxf(m, x);
            }
            float sum = 0.0f;
#pragma unroll
            for (int j = 0; j < KW; ++j) {
                float e = __expf(s[t][j] - m);
                s[t][j] = e;
                sum += e;
            }
            float inv = 1.0f / sum;
#pragma unroll
            for (int j = 0; j < KW; ++j)
                s[t][j] *= inv * vm[j];
        }
    }

    // ---- Pass 2: direct-global V, single rolling window --------------------
    // Row i's FMAs wait (compiler vmcnt) on the loads issued one phase ahead;
    // WAR ordering keeps refills after consumption.
    float o[TPT][CPT];
#pragma unroll
    for (int t = 0; t < TPT; ++t)
#pragma unroll
        for (int i = 0; i < CPT; ++i) o[t][i] = 0.0f;

#pragma unroll
    for (int i = 0; i < CPT; ++i) {
#pragma unroll
        for (int t = 0; t < TPT; ++t)
#pragma unroll
            for (int j = 0; j < KW; ++j)
                o[t][i] = fmaf(s[t][j], w[t + 3*j], o[t][i]);
        if (i < CPT - 1)
            vload_row(vg + (size_t)(cs * CPT + i + 1) * NPOS, w0, w);
    }

    // ---- Store: one NT float4 per token (128B/token across 8 cs lanes) ----
    const int b  = bh >> 4;
    const int hh = bh & (NH - 1);
#pragma unroll
    for (int t = 0; t < TPT; ++t) {
        float* op = out + ((size_t)(b * NPOS + n0 + t)) * DCH + hh * HD + cs * CPT;
        floatx4 val = {o[t][0], o[t][1], o[t][2], o[t][3]};
        __builtin_nontemporal_store(val, (floatx4*)op);
    }
}

extern "C" void kernel_launch(void* const* d_in, const int* in_sizes, int n_in,
                              void* d_out, int out_size, void* d_ws, size_t ws_size,
                              hipStream_t stream) {
    const float* q = (const float*)d_in[0];
    const float* k = (const float*)d_in[1];
    const float* v = (const float*)d_in[2];
    float* out = (float*)d_out;

    const int grid = 4 * NH * NTILES;   // 64 bh * 128 tiles = 8192 one-wave blocks
    hipLaunchKernelGGL(dilate_attn_kernel, dim3(grid), dim3(64), 0, stream,
                       q, k, v, out);
}